// Round 3
// baseline (111.975 us; speedup 1.0000x reference)
//
#include <hip/hip_runtime.h>

// Problem dims (static, match reference)
#define N_PIX (512*512)
#define NFEAT 8
#define NCLUS 8
#define NB    4
#define GRIDX 128                 // blocks per sample; 512 blocks total = 2/CU
#define NCHUNK (N_PIX/4)          // 65536 float4/int4 chunks per sample
#define STRIDE (GRIDX*256)        // 32768 -> compile-time 2 iterations/thread
#define PART_STRIDE 80            // per-(block,sample) floats: [0..63] sums f*8+c, [64..71] counts
#define DIST_OFF (GRIDX*NB*PART_STRIDE)   // 40960 floats
#define NREP_D 16                 // dist-accumulator replicas (atomic chain = GRIDX/NREP_D = 8)
#define CNT_OFF (DIST_OFF + NREP_D*NB)    // completion ticket (uint)

// ---------------------------------------------------------------------------
// Pass A: per-sample per-cluster feature sums + counts.
// Register select-FMA accumulation (NO atomics), ballot-based counts,
// 6-round reduce-scatter butterfly (lane L ends with wave total of entry L),
// block fold via tiny LDS, plain stores of per-block partials.
// (unchanged from round 2 — validated absmax 0.0)
// ---------------------------------------------------------------------------
__global__ __launch_bounds__(256) void k_sums(const float* __restrict__ pred,
                                              const int* __restrict__ tgt,
                                              float* __restrict__ ws) {
    const int tid = threadIdx.x;
    const int bx = blockIdx.x, b = blockIdx.y;
    const int lane = tid & 63, w = tid >> 6;

    float acc[64];
#pragma unroll
    for (int i = 0; i < 64; ++i) acc[i] = 0.0f;
    int cnt[8] = {0, 0, 0, 0, 0, 0, 0, 0};

    const int4*   t4 = (const int4*)(tgt + b * N_PIX);
    const float4* p4 = (const float4*)(pred + (size_t)b * NFEAT * N_PIX);

#pragma unroll
    for (int it = 0; it < NCHUNK / STRIDE; ++it) {
        const int i = bx * 256 + tid + it * STRIDE;
        int4 g4 = t4[i];
        int gs[4] = {g4.x, g4.y, g4.z, g4.w};
        float pr[NFEAT][4];
#pragma unroll
        for (int f = 0; f < NFEAT; ++f) {
            float4 v = p4[f * NCHUNK + i];
            pr[f][0] = v.x; pr[f][1] = v.y; pr[f][2] = v.z; pr[f][3] = v.w;
        }
#pragma unroll
        for (int j = 0; j < 4; ++j) {
            float m[NCLUS];
#pragma unroll
            for (int c = 0; c < NCLUS; ++c) {
                bool hit = (gs[j] == c);
                m[c] = hit ? 1.0f : 0.0f;
                cnt[c] += (int)__popcll(__ballot(hit));
            }
#pragma unroll
            for (int f = 0; f < NFEAT; ++f)
#pragma unroll
                for (int c = 0; c < NCLUS; ++c)
                    acc[f * 8 + c] = fmaf(m[c], pr[f][j], acc[f * 8 + c]);
        }
    }

    // Reduce-scatter butterfly: after 6 rounds acc[0] = wave total of entry
    // 'lane'. ~315 VALU ops vs 864 for a naive 72-entry butterfly.
#pragma unroll
    for (int k = 0; k < 6; ++k) {
        const int d = 1 << k;
        const int bit = (lane >> k) & 1;
#pragma unroll
        for (int p = 0; p < (64 >> 1); ++p) {
            if (p >= (64 >> (k + 1))) break;
            float a  = __shfl_xor(acc[2 * p],     d, 64);
            float bb = __shfl_xor(acc[2 * p + 1], d, 64);
            float own = bit ? acc[2 * p + 1] : acc[2 * p];
            float oth = bit ? bb : a;
            acc[p] = own + oth;
        }
    }

    __shared__ float ssum[4][64];
    __shared__ float scnt[4][8];
    ssum[w][lane] = acc[0];
    if (lane == 0) {
#pragma unroll
        for (int c = 0; c < NCLUS; ++c) scnt[w][c] = (float)cnt[c];
    }
    __syncthreads();

    if (tid < 72) {
        float s;
        if (tid < 64) s = ssum[0][tid] + ssum[1][tid] + ssum[2][tid] + ssum[3][tid];
        else { int c = tid - 64; s = scnt[0][c] + scnt[1][c] + scnt[2][c] + scnt[3][c]; }
        ws[(bx * NB + b) * PART_STRIDE + tid] = s;   // plain store, no atomic
    }
    // zero dist replicas + ticket (visible to k_var across the kernel boundary)
    if (tid == 0 && bx < NREP_D) ws[DIST_OFF + bx * NB + b] = 0.0f;
    if (tid == 0 && bx == 0 && b == 0) ((unsigned int*)(ws + CNT_OFF))[0] = 0u;
}

// ---------------------------------------------------------------------------
// Pass B + epilogue (fused via last-block pattern).
// Each block: fold partials -> means (LDS, stride-9 pad: banks 9g+f distinct
// over g), per-pixel clip(||mu_g - p||-0.5)^2, wave reduce, one fp atomic
// into 16 replicas, __threadfence, ticket. The 512th block runs the old
// k_final: re-reduces partials for all samples (k_sums data — safe across
// the kernel boundary) and reads dist replicas via coherent RMW
// (unsafeAtomicAdd(p, 0.0f)) since per-XCD L2s aren't plain-load coherent.
// ---------------------------------------------------------------------------
__global__ __launch_bounds__(256) void k_var(const float* __restrict__ pred,
                                             const int* __restrict__ tgt,
                                             float* __restrict__ ws,
                                             float* __restrict__ out) {
    __shared__ float raw[72];
    __shared__ float mean[NCLUS * 9];
    __shared__ float sl[4];
    __shared__ int lastFlag;
    const int tid = threadIdx.x;
    const int bx = blockIdx.x, b = blockIdx.y;

    if (tid < 72) {
        float s = 0.0f;
        for (int r = 0; r < GRIDX; ++r)
            s += ws[(r * NB + b) * PART_STRIDE + tid];
        raw[tid] = s;
    }
    __syncthreads();
    if (tid < 64) {
        const int f = tid >> 3, c = tid & 7;
        mean[c * 9 + f] = raw[f * 8 + c] / raw[64 + c];
    }
    __syncthreads();

    const int4*   t4 = (const int4*)(tgt + b * N_PIX);
    const float4* p4 = (const float4*)(pred + (size_t)b * NFEAT * N_PIX);

    float local = 0.0f;
#pragma unroll
    for (int it = 0; it < NCHUNK / STRIDE; ++it) {
        const int i = bx * 256 + tid + it * STRIDE;
        int4 g4 = t4[i];
        int gs[4] = {g4.x, g4.y, g4.z, g4.w};
        float pr[NFEAT][4];
#pragma unroll
        for (int f = 0; f < NFEAT; ++f) {
            float4 v = p4[f * NCHUNK + i];
            pr[f][0] = v.x; pr[f][1] = v.y; pr[f][2] = v.z; pr[f][3] = v.w;
        }
#pragma unroll
        for (int j = 0; j < 4; ++j) {
            const float* m = &mean[gs[j] * 9];
            float dsq = 0.0f;
#pragma unroll
            for (int f = 0; f < NFEAT; ++f) {
                float d = m[f] - pr[f][j];
                dsq = fmaf(d, d, dsq);
            }
            float diff = sqrtf(dsq);
            float dm = fminf(fmaxf(diff - 0.5f, 0.0f), 100000.0f);
            local = fmaf(dm, dm, local);
        }
    }

#pragma unroll
    for (int o = 32; o >= 1; o >>= 1) local += __shfl_xor(local, o, 64);
    if ((tid & 63) == 0) sl[tid >> 6] = local;
    __syncthreads();

    if (tid == 0) {
        unsafeAtomicAdd(&ws[DIST_OFF + (bx & (NREP_D - 1)) * NB + b],
                        sl[0] + sl[1] + sl[2] + sl[3]);
        __threadfence();   // publish dist partial before the ticket
        unsigned int t = atomicAdd((unsigned int*)(ws + CNT_OFF), 1u);
        lastFlag = (t == GRIDX * NB - 1) ? 1 : 0;
    }
    __syncthreads();
    if (!lastFlag) return;
    __threadfence();       // acquire: order replica reads after ticket read

    // ---- epilogue (old k_final), runs in exactly one block ----
    __shared__ float rawA[NB][72];
    __shared__ float distR[NREP_D * NB];
    __shared__ float distA[NB];
    __shared__ float meanL[NB][64];
    __shared__ float sl2[NB];

    for (int idx = tid; idx < NB * 72; idx += 256) {
        const int bb = idx / 72, e = idx - bb * 72;
        float s = 0.0f;
        for (int r = 0; r < GRIDX; ++r)
            s += ws[(r * NB + bb) * PART_STRIDE + e];
        rawA[bb][e] = s;
    }
    if (tid < NREP_D * NB)   // coherent read of other XCDs' fp atomics
        distR[tid] = unsafeAtomicAdd(&ws[DIST_OFF + tid], 0.0f);
    __syncthreads();
    if (tid < NB) {
        float s = 0.0f;
#pragma unroll
        for (int r = 0; r < NREP_D; ++r) s += distR[r * NB + tid];
        distA[tid] = s;
    }
    __syncthreads();

    const int b2 = tid >> 6, idx = tid & 63;
    meanL[b2][idx] = rawA[b2][idx] / rawA[b2][64 + (idx & 7)];
    __syncthreads();

    const int i = idx >> 3, j = idx & 7;
    float pdsq = 0.0f;
#pragma unroll
    for (int f = 0; f < 8; ++f) {
        float d = meanL[b2][f * 8 + i] - meanL[b2][f * 8 + j];
        pdsq = fmaf(d, d, pdsq);
    }
    float nrm = sqrtf(pdsq);
    float t2 = fminf(fmaxf(3.0f - nrm, 0.0f), 100000.0f);   // margin = 2*delta_d
    float val = (i == j) ? 0.0f : t2 * t2 * (1.0f / 56.0f); // / (C*(C-1))

    if (i == 0) {
        float rsq = 0.0f;
#pragma unroll
        for (int f = 0; f < 8; ++f) {
            float m = meanL[b2][f * 8 + j];
            rsq = fmaf(m, m, rsq);
        }
        float invc = 1.0f / rawA[b2][64 + j];
        val += 0.001f * sqrtf(rsq) * 0.125f + distA[b2] * invc * 0.125f;
    }

#pragma unroll
    for (int o = 32; o >= 1; o >>= 1) val += __shfl_xor(val, o, 64);
    if (idx == 0) sl2[b2] = val;
    __syncthreads();
    if (tid == 0) out[0] = (sl2[0] + sl2[1] + sl2[2] + sl2[3]) * 0.25f;
}

// ---------------------------------------------------------------------------
extern "C" void kernel_launch(void* const* d_in, const int* in_sizes, int n_in,
                              void* d_out, int out_size, void* d_ws, size_t ws_size,
                              hipStream_t stream) {
    const float* pred = (const float*)d_in[0];
    const int*   tgt  = (const int*)d_in[1];
    float* out = (float*)d_out;
    float* ws  = (float*)d_ws;

    dim3 grid(GRIDX, NB);   // 512 blocks, 2/CU
    k_sums<<<grid, 256, 0, stream>>>(pred, tgt, ws);   // zeroes replicas + ticket
    k_var <<<grid, 256, 0, stream>>>(pred, tgt, ws, out);
}

// Round 4
// 87.066 us; speedup vs baseline: 1.2861x; 1.2861x over previous
//
#include <hip/hip_runtime.h>

// Problem dims (static, match reference)
#define N_PIX (512*512)
#define NFEAT 8
#define NCLUS 8
#define NB    4
#define GRIDX 128                 // blocks per sample; 512 blocks total = 2/CU
#define NCHUNK (N_PIX/4)          // 65536 float4/int4 chunks per sample
#define STRIDE (GRIDX*256)        // 32768 -> compile-time 2 iterations/thread
// Workspace layout (floats). Partials transposed for contiguous fold:
//   P[e][b][r] at e*512 + b*128 + r,  e in [0,72): 64 sums (f*8+c) + 8 counts
#define PART_TOTAL (72*NB*GRIDX)          // 36864
#define DIST_OFF  PART_TOTAL              // 512 per-block dist partials
#define S2_OFF    (DIST_OFF + NB*GRIDX)   // staged per-sample totals, stride 72
// Every ws location we read is written earlier in the same call -> no init
// needed; safe against the harness 0xAA poison.

// ---------------------------------------------------------------------------
// Pass A: per-sample per-cluster feature sums + counts.
// Register select-FMA accumulation (no atomics), ballot counts, 6-round
// reduce-scatter butterfly (lane L ends with wave total of entry L), block
// fold via LDS, plain transposed stores. (math identical to round 2,
// absmax 0.0)
// ---------------------------------------------------------------------------
__global__ __launch_bounds__(256) void k_sums(const float* __restrict__ pred,
                                              const int* __restrict__ tgt,
                                              float* __restrict__ ws) {
    const int tid = threadIdx.x;
    const int bx = blockIdx.x, b = blockIdx.y;
    const int lane = tid & 63, w = tid >> 6;

    float acc[64];
#pragma unroll
    for (int i = 0; i < 64; ++i) acc[i] = 0.0f;
    int cnt[8] = {0, 0, 0, 0, 0, 0, 0, 0};

    const int4*   t4 = (const int4*)(tgt + b * N_PIX);
    const float4* p4 = (const float4*)(pred + (size_t)b * NFEAT * N_PIX);

#pragma unroll
    for (int it = 0; it < NCHUNK / STRIDE; ++it) {
        const int i = bx * 256 + tid + it * STRIDE;
        int4 g4 = t4[i];
        int gs[4] = {g4.x, g4.y, g4.z, g4.w};
        float pr[NFEAT][4];
#pragma unroll
        for (int f = 0; f < NFEAT; ++f) {
            float4 v = p4[f * NCHUNK + i];
            pr[f][0] = v.x; pr[f][1] = v.y; pr[f][2] = v.z; pr[f][3] = v.w;
        }
#pragma unroll
        for (int j = 0; j < 4; ++j) {
            float m[NCLUS];
#pragma unroll
            for (int c = 0; c < NCLUS; ++c) {
                bool hit = (gs[j] == c);
                m[c] = hit ? 1.0f : 0.0f;
                cnt[c] += (int)__popcll(__ballot(hit));
            }
#pragma unroll
            for (int f = 0; f < NFEAT; ++f)
#pragma unroll
                for (int c = 0; c < NCLUS; ++c)
                    acc[f * 8 + c] = fmaf(m[c], pr[f][j], acc[f * 8 + c]);
        }
    }

    // Reduce-scatter butterfly: after 6 rounds acc[0] = wave total of entry
    // 'lane'.
#pragma unroll
    for (int k = 0; k < 6; ++k) {
        const int d = 1 << k;
        const int bit = (lane >> k) & 1;
#pragma unroll
        for (int p = 0; p < (64 >> 1); ++p) {
            if (p >= (64 >> (k + 1))) break;
            float a  = __shfl_xor(acc[2 * p],     d, 64);
            float bb = __shfl_xor(acc[2 * p + 1], d, 64);
            float own = bit ? acc[2 * p + 1] : acc[2 * p];
            float oth = bit ? bb : a;
            acc[p] = own + oth;
        }
    }

    __shared__ float ssum[4][64];
    __shared__ float scnt[4][8];
    ssum[w][lane] = acc[0];
    if (lane == 0) {
#pragma unroll
        for (int c = 0; c < NCLUS; ++c) scnt[w][c] = (float)cnt[c];
    }
    __syncthreads();

    if (tid < 72) {
        float s;
        if (tid < 64) s = ssum[0][tid] + ssum[1][tid] + ssum[2][tid] + ssum[3][tid];
        else { int c = tid - 64; s = scnt[0][c] + scnt[1][c] + scnt[2][c] + scnt[3][c]; }
        ws[tid * (NB * GRIDX) + b * GRIDX + bx] = s;   // transposed plain store
    }
}

// ---------------------------------------------------------------------------
// Pass B: Sum clip(||mu_g - p|| - 0.5, 0, 1e5)^2 over pixels.
// Prologue: 288 (entry,quad) slots over 256 threads fold 32 contiguous
// partials each via 8 independent float4 loads (chain depth 8, was 128).
// Means in LDS stride-9 pad (banks 9g+f distinct over g -> conflict-free).
// Epilogue: plain store of the block's dist partial. NO atomics anywhere.
// ---------------------------------------------------------------------------
__global__ __launch_bounds__(256) void k_var(const float* __restrict__ pred,
                                             const int* __restrict__ tgt,
                                             float* __restrict__ ws) {
    __shared__ float pp[72][4];
    __shared__ float raw[72];
    __shared__ float mean[NCLUS * 9];
    __shared__ float sl[4];
    const int tid = threadIdx.x;
    const int bx = blockIdx.x, b = blockIdx.y;

    for (int s = tid; s < 288; s += 256) {
        const int e = s >> 2, q = s & 3;
        const float4* src = (const float4*)(ws + e * (NB * GRIDX) + b * GRIDX) + q * 8;
        float4 a0 = src[0], a1 = src[1], a2 = src[2], a3 = src[3];
        float4 a4 = src[4], a5 = src[5], a6 = src[6], a7 = src[7];
        float r0 = (a0.x + a0.y + a0.z + a0.w) + (a1.x + a1.y + a1.z + a1.w);
        float r1 = (a2.x + a2.y + a2.z + a2.w) + (a3.x + a3.y + a3.z + a3.w);
        float r2 = (a4.x + a4.y + a4.z + a4.w) + (a5.x + a5.y + a5.z + a5.w);
        float r3 = (a6.x + a6.y + a6.z + a6.w) + (a7.x + a7.y + a7.z + a7.w);
        pp[e][q] = (r0 + r1) + (r2 + r3);
    }
    __syncthreads();
    if (tid < 72) {
        float s = (pp[tid][0] + pp[tid][1]) + (pp[tid][2] + pp[tid][3]);
        raw[tid] = s;
        if (bx == 0) ws[S2_OFF + b * 72 + tid] = s;   // stage for k_final
    }
    __syncthreads();
    if (tid < 64) {
        const int f = tid >> 3, c = tid & 7;
        mean[c * 9 + f] = raw[f * 8 + c] / raw[64 + c];
    }
    __syncthreads();

    const int4*   t4 = (const int4*)(tgt + b * N_PIX);
    const float4* p4 = (const float4*)(pred + (size_t)b * NFEAT * N_PIX);

    float local = 0.0f;
#pragma unroll
    for (int it = 0; it < NCHUNK / STRIDE; ++it) {
        const int i = bx * 256 + tid + it * STRIDE;
        int4 g4 = t4[i];
        int gs[4] = {g4.x, g4.y, g4.z, g4.w};
        float pr[NFEAT][4];
#pragma unroll
        for (int f = 0; f < NFEAT; ++f) {
            float4 v = p4[f * NCHUNK + i];
            pr[f][0] = v.x; pr[f][1] = v.y; pr[f][2] = v.z; pr[f][3] = v.w;
        }
#pragma unroll
        for (int j = 0; j < 4; ++j) {
            const float* m = &mean[gs[j] * 9];
            float dsq = 0.0f;
#pragma unroll
            for (int f = 0; f < NFEAT; ++f) {
                float d = m[f] - pr[f][j];
                dsq = fmaf(d, d, dsq);
            }
            float diff = sqrtf(dsq);
            float dm = fminf(fmaxf(diff - 0.5f, 0.0f), 100000.0f);
            local = fmaf(dm, dm, local);
        }
    }

#pragma unroll
    for (int o = 32; o >= 1; o >>= 1) local += __shfl_xor(local, o, 64);
    if ((tid & 63) == 0) sl[tid >> 6] = local;
    __syncthreads();
    if (tid == 0)
        ws[DIST_OFF + bx * NB + b] = sl[0] + sl[1] + sl[2] + sl[3];  // plain store
}

// ---------------------------------------------------------------------------
// Pass C: tiny epilogue, one block. Tree-reduces the 512 dist partials in LDS
// (stride multiples of 4 preserve the sample index b = idx&3), then the
// validated l_dist / l_reg / l_var-quirk math from round 2.
// ---------------------------------------------------------------------------
__global__ __launch_bounds__(256) void k_final(const float* __restrict__ ws,
                                               float* __restrict__ out) {
    __shared__ float sd[256];
    __shared__ float meanL[NB][64];
    __shared__ float sl[NB];
    const int tid = threadIdx.x;

    sd[tid] = ws[DIST_OFF + tid] + ws[DIST_OFF + 256 + tid];
    __syncthreads();
#pragma unroll
    for (int off = 128; off >= 4; off >>= 1) {
        if (tid < off) sd[tid] += sd[tid + off];
        __syncthreads();
    }
    // sd[0..3] = per-sample dist totals (index mod 4 == b preserved)

    const int b = tid >> 6, idx = tid & 63;
    const float* S2 = ws + S2_OFF + b * 72;
    meanL[b][idx] = S2[idx] / S2[64 + (idx & 7)];
    __syncthreads();

    const int i = idx >> 3, j = idx & 7;
    float pdsq = 0.0f;
#pragma unroll
    for (int f = 0; f < 8; ++f) {
        float d = meanL[b][f * 8 + i] - meanL[b][f * 8 + j];
        pdsq = fmaf(d, d, pdsq);
    }
    float nrm = sqrtf(pdsq);
    float t = fminf(fmaxf(3.0f - nrm, 0.0f), 100000.0f);   // margin = 2*delta_d
    float val = (i == j) ? 0.0f : t * t * (1.0f / 56.0f);  // / (C*(C-1))

    if (i == 0) {
        float rsq = 0.0f;
#pragma unroll
        for (int f = 0; f < 8; ++f) {
            float m = meanL[b][f * 8 + j];
            rsq = fmaf(m, m, rsq);
        }
        float invc = 1.0f / S2[64 + j];
        val += 0.001f * sqrtf(rsq) * 0.125f + sd[b] * invc * 0.125f;
    }

#pragma unroll
    for (int o = 32; o >= 1; o >>= 1) val += __shfl_xor(val, o, 64);
    if (idx == 0) sl[b] = val;
    __syncthreads();
    if (tid == 0) out[0] = (sl[0] + sl[1] + sl[2] + sl[3]) * 0.25f;
}

// ---------------------------------------------------------------------------
extern "C" void kernel_launch(void* const* d_in, const int* in_sizes, int n_in,
                              void* d_out, int out_size, void* d_ws, size_t ws_size,
                              hipStream_t stream) {
    const float* pred = (const float*)d_in[0];
    const int*   tgt  = (const int*)d_in[1];
    float* out = (float*)d_out;
    float* ws  = (float*)d_ws;

    dim3 grid(GRIDX, NB);   // 512 blocks, 2/CU
    k_sums<<<grid, 256, 0, stream>>>(pred, tgt, ws);
    k_var <<<grid, 256, 0, stream>>>(pred, tgt, ws);
    k_final<<<1, 256, 0, stream>>>(ws, out);
}